// Round 1
// baseline (1387.409 us; speedup 1.0000x reference)
//
#include <hip/hip_runtime.h>

// out[b,j] = sum_i x[b,i,i] * P[i,j]   (P rows are one-hot)
// dim = 8855, B = 4, NVAL = 15 -> out has 60 floats.
//
// Single fused launch: block b computes out[b,:] entirely.
//  - LDS bins + plain final stores -> no global atomics, no pre-zero kernel
//    (every one of the 60 poisoned output floats is overwritten).
//  - 9 diagonal loads per thread issued up-front (static unroll) for MLP
//    latency overlap; statically-indexed register arrays (no scratch).

#define NVAL 15
#define BLK 1024
#define KITER 9   // ceil(8855 / 1024)

__global__ __launch_bounds__(BLK) void diag_proj_fused(
        const float* __restrict__ x,   // [B, dim, dim]
        const float* __restrict__ P,   // [dim, NVAL]
        float* __restrict__ out,       // [B, NVAL]
        int dim) {
    __shared__ float bins[NVAL];
    const int t = threadIdx.x;
    const int b = blockIdx.x;

    if (t < NVAL) bins[t] = 0.0f;
    __syncthreads();

    const size_t base   = (size_t)b * (size_t)dim * (size_t)dim;
    const size_t dstride = (size_t)dim + 1;   // diagonal stride

    float d[KITER];
    int   j[KITER];

    // Phase 1: issue all independent loads (diag + one-hot search) first.
#pragma unroll
    for (int k = 0; k < KITER; ++k) {
        const int i = t + k * BLK;
        if (i < dim) {
            d[k] = x[base + (size_t)i * dstride];
            const float* __restrict__ prow = P + (size_t)i * NVAL;
            int jj = 0;
#pragma unroll
            for (int c = 0; c < NVAL; ++c) {
                if (prow[c] != 0.0f) jj = c;
            }
            j[k] = jj;
        } else {
            d[k] = 0.0f;   // adding 0 to bin 0 is harmless
            j[k] = 0;
        }
    }

    // Generic tail in case dim > BLK*KITER (dead for dim = 8855).
    for (int i = t + BLK * KITER; i < dim; i += BLK) {
        const float dv = x[base + (size_t)i * dstride];
        const float* __restrict__ prow = P + (size_t)i * NVAL;
        int jj = 0;
#pragma unroll
        for (int c = 0; c < NVAL; ++c) {
            if (prow[c] != 0.0f) jj = c;
        }
        atomicAdd(&bins[jj], dv);
    }

    // Phase 2: LDS accumulation.
#pragma unroll
    for (int k = 0; k < KITER; ++k) {
        atomicAdd(&bins[j[k]], d[k]);
    }
    __syncthreads();

    // Phase 3: direct store — overwrites all poisoned output bytes.
    if (t < NVAL) out[b * NVAL + t] = bins[t];
}

extern "C" void kernel_launch(void* const* d_in, const int* in_sizes, int n_in,
                              void* d_out, int out_size, void* d_ws, size_t ws_size,
                              hipStream_t stream) {
    const float* x = (const float*)d_in[0];
    const float* P = (const float*)d_in[1];
    float* out = (float*)d_out;

    const int dim = in_sizes[1] / NVAL;                             // 8855
    const int B   = (int)(in_sizes[0] / ((long long)dim * dim));    // 4

    diag_proj_fused<<<dim3(B), dim3(BLK), 0, stream>>>(x, P, out, dim);
}

// Round 2
// 1295.569 us; speedup vs baseline: 1.0709x; 1.0709x over previous
//
#include <hip/hip_runtime.h>

// out[b,j] = sum_i x[b,i,i] * P[i,j]   (P rows are one-hot)
// dim = 8855, B = 4, NVAL = 15 -> out has 60 floats.
//
// Structure notes (verified across sessions at ~1302 us):
//  - grid (ceil(dim/256), B) = 140 blocks -> spreads the 35,420 inherently
//    uncoalesced diagonal-line loads across all CUs (round-1 experiment with
//    4 blocks cost +85 us from lost memory-level parallelism).
//  - out is poisoned before every timed launch, and multiple blocks
//    accumulate into it -> tiny zero kernel first (launch overhead under
//    graph capture is ~2 us; fusing is not worth the parallelism risk).

#define NVAL 15

__global__ __launch_bounds__(64) void zero_out_kernel(float* out, int n) {
    int t = threadIdx.x;
    if (t < n) out[t] = 0.0f;
}

__global__ __launch_bounds__(256) void diag_proj_kernel(
        const float* __restrict__ x,   // [B, dim, dim]
        const float* __restrict__ P,   // [dim, NVAL]
        float* __restrict__ out,       // [B, NVAL]
        int dim) {
    __shared__ float bins[NVAL];
    const int t = threadIdx.x;
    if (t < NVAL) bins[t] = 0.0f;
    __syncthreads();

    const int i = blockIdx.x * blockDim.x + t;
    const int b = blockIdx.y;

    if (i < dim) {
        // diagonal element: stride dim+1 within batch b
        const size_t base = (size_t)b * (size_t)dim * (size_t)dim;
        const float d = x[base + (size_t)i * (size_t)(dim + 1)];

        // find the single nonzero column of P row i (branchless scan;
        // P is ~531 KB -> L2-resident, loads are cheap)
        const float* __restrict__ prow = P + (size_t)i * NVAL;
        int j = 0;
#pragma unroll
        for (int jj = 0; jj < NVAL; ++jj) {
            j += (prow[jj] != 0.0f) ? jj : 0;
        }
        atomicAdd(&bins[j], d);
    }
    __syncthreads();

    if (t < NVAL) {
        const float v = bins[t];
        if (v != 0.0f) atomicAdd(&out[b * NVAL + t], v);
    }
}

extern "C" void kernel_launch(void* const* d_in, const int* in_sizes, int n_in,
                              void* d_out, int out_size, void* d_ws, size_t ws_size,
                              hipStream_t stream) {
    const float* x = (const float*)d_in[0];
    const float* P = (const float*)d_in[1];
    float* out = (float*)d_out;

    const int dim = in_sizes[1] / NVAL;                             // 8855
    const int B   = (int)(in_sizes[0] / ((long long)dim * dim));    // 4

    // d_out is poisoned 0xAA before every timed launch -> zero it first.
    // out_size = 60 floats -> one wave.
    zero_out_kernel<<<1, 64, 0, stream>>>(out, out_size);

    dim3 grid((dim + 255) / 256, B);
    diag_proj_kernel<<<grid, 256, 0, stream>>>(x, P, out, dim);
}